// Round 2
// 792.227 us; speedup vs baseline: 1.2102x; 1.2102x over previous
//
#include <hip/hip_runtime.h>
#include <math.h>

#define NPATH 19
#define NCOL 2160
#define NCLASS 81

// Path tables in generation order p0..p18:
// (l1,l2,l3) per path; input offsets; CG tensor offsets; class bases.
__constant__ int P_OFF1[NPATH] = {0,0,0, 64,64,64,64,64,64,64, 160,160,160,160,160,160,160,160,160};
__constant__ int P_D1[NPATH]   = {1,1,1, 3,3,3,3,3,3,3, 5,5,5,5,5,5,5,5,5};
__constant__ int P_OFF2[NPATH] = {0,1,4, 0,1,1,1,4,4,4, 0,1,1,1,4,4,4,4,4};
__constant__ int P_L1[NPATH]   = {0,0,0, 1,1,1,1,1,1,1, 2,2,2,2,2,2,2,2,2};
__constant__ int P_L2[NPATH]   = {0,1,2, 0,1,1,1,2,2,2, 0,1,1,1,2,2,2,2,2};
__constant__ int P_L3[NPATH]   = {0,1,2, 1,0,1,2,1,2,3, 2,1,2,3,0,1,2,3,4};
__constant__ int P_CGOFF[NPATH]= {0,1,10,35,44,53,80,125,170,245,350,375,420,495,600,625,700,825,1000};
__constant__ int P_CLSBASE[NPATH]={0,1,4,9,12,13,16,21,24,29,36,41,44,49,56,57,60,65,72};
// e3nn output irrep sort (stable by key (l3, -p3*(-1)^l3)):
// 0e:{0,4,14} 1o:{1,3,7,11} 1e:{5,15} 2e:{2,6,10,16} 2o:{8,12} 3o:{9,13} 3e:{17} 4e:{18}
__constant__ int S_PATH[NPATH] = {0,4,14, 1,3,7,11, 5,15, 2,6,10,16, 8,12, 9,13, 17,18};
__constant__ int S_OFF[NPATH+1]= {0,64,96,112,304,400,496,544,640,688,1008,1168,1248,1328,1488,1568,1792,1904,2016,2160};

// Exact factorial table (all factorial args in this problem are <= 9; doubles are exact).
__constant__ double FACT[13] = {1.0,1.0,2.0,6.0,24.0,120.0,720.0,5040.0,40320.0,362880.0,
                                3628800.0,39916800.0,479001600.0};

struct cpx { double r, i; };
__device__ inline cpx cmul(cpx a, cpx b){ cpx o; o.r=a.r*b.r-a.i*b.i; o.i=a.r*b.i+a.i*b.r; return o; }

__device__ double su2cg(int j1,int j2,int j3,int m1,int m2,int m3){
  if (m1+m2 != m3) return 0.0;
  int vmin = max(max(-j1+j2+m3, -j1+m1), 0);
  int vmax = min(min(j2+j3+m1, j3-j1+j2), j3+m3);
  if (vmin > vmax) return 0.0;
  double C = sqrt((2.0*j3+1.0)*FACT[j3+j1-j2]*FACT[j3-j1+j2]*FACT[j1+j2-j3]/FACT[j1+j2+j3+1])
           * sqrt(FACT[j3+m3]*FACT[j3-m3]*FACT[j1-m1]*FACT[j1+m1]*FACT[j2-m2]*FACT[j2+m2]);
  double S = 0.0;
  for (int v=vmin; v<=vmax; v++){
    double sgn = ((v+j2+m2)&1) ? -1.0 : 1.0;
    S += sgn * FACT[j2+j3+m1-v]*FACT[j1-m1+v]
         / (FACT[v]*FACT[j3-j1+j2-v]*FACT[j3+m3-v]*FACT[v+j1-j2-m3]);
  }
  return C*S;
}

// real->complex change-of-basis matrix, times (-i)^l (e3nn convention)
__device__ void buildQ(int l, double* qr, double* qi){
  int d = 2*l+1;
  for (int x=0;x<d*d;x++){ qr[x]=0.0; qi[x]=0.0; }
  const double s2 = 0.70710678118654752440;
  for (int m=-l; m<0; m++){
    int r = l+m;
    qr[r*d + (l-m)] = s2;      // q[l+m, l+|m|] = 1/sqrt2
    qi[r*d + (l+m)] = -s2;     // q[l+m, l-|m|] = -i/sqrt2
  }
  qr[l*d+l] = 1.0;
  for (int m=1; m<=l; m++){
    int r=l+m; double sg = (m&1)? -1.0 : 1.0;
    qr[r*d + (l+m)] = sg*s2;   // (-1)^m/sqrt2
    qi[r*d + (l-m)] = sg*s2;   // i*(-1)^m/sqrt2
  }
  int ph = l & 3;              // multiply by (-i)^l
  if (ph){
    for (int x=0;x<d*d;x++){
      double a=qr[x], b=qi[x];
      if (ph==1){ qr[x]=b;  qi[x]=-a; }
      else if (ph==2){ qr[x]=-a; qi[x]=-b; }
      else { qr[x]=-b; qi[x]=a; }
    }
  }
}

// Stage 1: one block per path (19 blocks run concurrently on separate CUs).
// Computes the real-basis CG for its path, normalizes, writes float CG to wsCg.
extern "C" __global__ void __launch_bounds__(256)
setup_cg(float* wsCg){
  __shared__ double Q1r[25], Q1i[25], Q2r[25], Q2i[25], Q3r[81], Q3i[81];
  __shared__ double su2[225];
  __shared__ double red[4];
  __shared__ double scaleSh;

  int p = blockIdx.x;
  int tid = threadIdx.x;
  int l1=P_L1[p], l2=P_L2[p], l3=P_L3[p];
  int d1=2*l1+1, d2=2*l2+1, d3=2*l3+1;
  int n = d1*d2*d3;

  // Q builds on three different waves -> run in parallel
  if (tid==0)        buildQ(l1,Q1r,Q1i);
  else if (tid==64)  buildQ(l2,Q2r,Q2i);
  else if (tid==128) buildQ(l3,Q3r,Q3i);
  if (tid < n){
    int c = tid % d3; int rem = tid / d3; int b = rem % d2; int a = rem / d2;
    su2[tid] = su2cg(l1,l2,l3, a-l1, b-l2, c-l3);
  }
  __syncthreads();

  double myval = 0.0;
  if (tid < n){
    int c = tid % d3; int rem = tid / d3; int b = rem % d2; int a = rem / d2;
    cpx s; s.r=0.0; s.i=0.0;
    int i1=2*l1-a, k1=2*l2-b, n1=2*l3-c;
    for (int ii=0; ii<2; ii++){
      int i = ii ? i1 : a; if (ii && i1==a) break;
      cpx q1; q1.r=Q1r[i*d1+a]; q1.i=Q1i[i*d1+a];
      for (int kk=0; kk<2; kk++){
        int k = kk ? k1 : b; if (kk && k1==b) break;
        cpx q2; q2.r=Q2r[k*d2+b]; q2.i=Q2i[k*d2+b];
        cpx q12 = cmul(q1,q2);
        for (int nn2=0; nn2<2; nn2++){
          int nn = nn2 ? n1 : c; if (nn2 && n1==c) break;
          cpx q3c; q3c.r=Q3r[nn*d3+c]; q3c.i=-Q3i[nn*d3+c];
          cpx t = cmul(q12, q3c);
          double w = su2[(i*d2+k)*d3+nn];
          s.r += t.r*w; s.i += t.i*w;
        }
      }
    }
    myval = s.r;  // imag part is structurally ~0
  }
  // Frobenius norm via block reduction
  double v = myval*myval;
  for (int off=32; off>0; off>>=1) v += __shfl_down(v, off, 64);
  if ((tid&63)==0) red[tid>>6] = v;
  __syncthreads();
  if (tid==0){
    double tot = red[0]+red[1]+red[2]+red[3];
    scaleSh = sqrt((double)d3) / sqrt(tot);   // 'component' norm: cg *= sqrt(d3)
  }
  __syncthreads();
  if (tid < n) wsCg[P_CGOFF[p] + tid] = (float)(myval * scaleSh);
}

// Stage 2: one block builds the sparse term tables + per-column meta from wsCg.
// wsHdr[0]=nTerms; wsMeta[2160] packed (start|cnt<<11|x1base<<16);
// wsTerms[nTerms] = {j*240+i_local, float_as_int(cg_val)} grouped per class (path,k).
extern "C" __global__ void __launch_bounds__(256)
setup_tables(const float* __restrict__ wsCg, int* wsHdr, int* wsMeta, int2* wsTerms){
  __shared__ float cgAll[1225];
  __shared__ int counts[NCLASS], ptrs[NCLASS+1];

  int tid = threadIdx.x;
  for (int t = tid; t < 1225; t += 256) cgAll[t] = wsCg[t];
  __syncthreads();

  // per-class nonzero counts
  if (tid < NCLASS){
    int p=0; while (p+1<NPATH && tid >= P_CLSBASE[p+1]) p++;
    int k = tid - P_CLSBASE[p];
    int d1=2*P_L1[p]+1, d2=2*P_L2[p]+1, d3=2*P_L3[p]+1;
    int cnt=0;
    for (int a=0;a<d1;a++) for (int b=0;b<d2;b++)
      if (fabsf(cgAll[P_CGOFF[p] + (a*d2+b)*d3 + k]) > 1e-4f) cnt++;
    counts[tid]=cnt;
  }
  __syncthreads();
  if (tid==0){
    int s=0; for (int q=0;q<NCLASS;q++){ ptrs[q]=s; s+=counts[q]; } ptrs[NCLASS]=s; wsHdr[0]=s;
  }
  __syncthreads();
  // emit terms per class
  if (tid < NCLASS){
    int p=0; while (p+1<NPATH && tid >= P_CLSBASE[p+1]) p++;
    int k = tid - P_CLSBASE[p];
    int d1=2*P_L1[p]+1, d2=2*P_L2[p]+1, d3=2*P_L3[p]+1;
    int w = ptrs[tid];
    for (int a=0;a<d1;a++) for (int b=0;b<d2;b++){
      float val = cgAll[P_CGOFF[p] + (a*d2+b)*d3 + k];
      if (fabsf(val) > 1e-4f){
        int idx = (P_OFF2[p]+b)*240 + a;   // index into P[j][i] (i_local part; x1base added at use)
        wsTerms[w] = make_int2(idx, __float_as_int(val));
        w++;
      }
    }
  }
  // per-column meta (output permutation baked into S_OFF/S_PATH)
  for (int c = tid; c < NCOL; c += 256){
    int j=0; while (c >= S_OFF[j+1]) j++;
    int p = S_PATH[j];
    int d3 = 2*P_L3[p]+1;
    int rel = c - S_OFF[j];
    int u = rel / d3, k = rel - u*d3;
    int cls = P_CLSBASE[p] + k;
    int start = ptrs[cls];
    int cnt = ptrs[cls+1]-ptrs[cls];
    int xb = P_OFF1[p] + u*P_D1[p];
    wsMeta[c] = start | (cnt<<11) | (xb<<16);
  }
}

// One block per row. P[j*240+i] = x2[j]*x1[i] in LDS; each output column is a
// short sparse dot over the class term table (L1-resident). float4 stores.
extern "C" __global__ void __launch_bounds__(256)
tp_kernel(const float* __restrict__ x1, const float* __restrict__ x2,
          float* __restrict__ out,
          const int* __restrict__ meta, const int2* __restrict__ terms,
          int nrows)
{
  __shared__ float Pp[NCOL];
  int row = blockIdx.x;
  if (row >= nrows) return;
  int tid = threadIdx.x;
  const float* x1r = x1 + (size_t)row*240;
  const float* x2r = x2 + (size_t)row*9;
  for (int t = tid; t < NCOL; t += 256){
    int j = t / 240;
    int i = t - j*240;
    Pp[t] = x2r[j] * x1r[i];
  }
  __syncthreads();
  float* outr = out + (size_t)row*NCOL;
  for (int base = tid*4; base < NCOL; base += 1024){
    int4 m4 = *(const int4*)(meta + base);
    int ms[4] = {m4.x, m4.y, m4.z, m4.w};
    float oarr[4];
    #pragma unroll
    for (int q=0;q<4;q++){
      int m = ms[q];
      int start = m & 2047;
      int cnt = (m>>11)&31;
      int xb = (m>>16)&255;
      float acc = 0.f;
      for (int t=0;t<cnt;t++){
        int2 tv = terms[start+t];
        acc += __int_as_float(tv.y) * Pp[tv.x + xb];
      }
      oarr[q] = acc;
    }
    float4 o; o.x=oarr[0]; o.y=oarr[1]; o.z=oarr[2]; o.w=oarr[3];
    *(float4*)(outr + base) = o;
  }
}

extern "C" void kernel_launch(void* const* d_in, const int* in_sizes, int n_in,
                              void* d_out, int out_size, void* d_ws, size_t ws_size,
                              hipStream_t stream) {
  const float* x1 = (const float*)d_in[0];
  const float* x2 = (const float*)d_in[1];
  float* out = (float*)d_out;
  int nrows = in_sizes[0] / 240;

  int* ws = (int*)d_ws;
  int* hdr   = ws;                    // [0]: nTerms
  int* meta  = ws + 64;               // 2160 ints, 16B-aligned
  int2* terms = (int2*)(ws + 4096);   // capacity 1344 terms (dense bound 1225)
  float* cgbuf = (float*)(ws + 7168); // 1225 floats of normalized CG values

  setup_cg<<<dim3(NPATH), dim3(256), 0, stream>>>(cgbuf);
  setup_tables<<<dim3(1), dim3(256), 0, stream>>>(cgbuf, hdr, meta, terms);
  tp_kernel<<<dim3(nrows), dim3(256), 0, stream>>>(x1, x2, out, meta, terms, nrows);
}

// Round 3
// 567.760 us; speedup vs baseline: 1.6887x; 1.3954x over previous
//
#include <hip/hip_runtime.h>
#include <math.h>

#define NPATH 19
#define NCOL 2160
#define NCLASS 81
#define CAP_TERMS 1344

// Path tables in generation order p0..p18:
// (l1,l2,l3) per path; input offsets; CG tensor offsets; class bases.
__constant__ int P_OFF1[NPATH] = {0,0,0, 64,64,64,64,64,64,64, 160,160,160,160,160,160,160,160,160};
__constant__ int P_D1[NPATH]   = {1,1,1, 3,3,3,3,3,3,3, 5,5,5,5,5,5,5,5,5};
__constant__ int P_OFF2[NPATH] = {0,1,4, 0,1,1,1,4,4,4, 0,1,1,1,4,4,4,4,4};
__constant__ int P_L1[NPATH]   = {0,0,0, 1,1,1,1,1,1,1, 2,2,2,2,2,2,2,2,2};
__constant__ int P_L2[NPATH]   = {0,1,2, 0,1,1,1,2,2,2, 0,1,1,1,2,2,2,2,2};
__constant__ int P_L3[NPATH]   = {0,1,2, 1,0,1,2,1,2,3, 2,1,2,3,0,1,2,3,4};
__constant__ int P_CGOFF[NPATH]= {0,1,10,35,44,53,80,125,170,245,350,375,420,495,600,625,700,825,1000};
__constant__ int P_CLSBASE[NPATH]={0,1,4,9,12,13,16,21,24,29,36,41,44,49,56,57,60,65,72};
// e3nn output irrep sort (stable by key (l3, -p3*(-1)^l3)):
// 0e:{0,4,14} 1o:{1,3,7,11} 1e:{5,15} 2e:{2,6,10,16} 2o:{8,12} 3o:{9,13} 3e:{17} 4e:{18}
__constant__ int S_PATH[NPATH] = {0,4,14, 1,3,7,11, 5,15, 2,6,10,16, 8,12, 9,13, 17,18};
__constant__ int S_OFF[NPATH+1]= {0,64,96,112,304,400,496,544,640,688,1008,1168,1248,1328,1488,1568,1792,1904,2016,2160};

// Exact factorial table (all factorial args in this problem are <= 9; doubles are exact).
__constant__ double FACT[13] = {1.0,1.0,2.0,6.0,24.0,120.0,720.0,5040.0,40320.0,362880.0,
                                3628800.0,39916800.0,479001600.0};

struct cpx { double r, i; };
__device__ inline cpx cmul(cpx a, cpx b){ cpx o; o.r=a.r*b.r-a.i*b.i; o.i=a.r*b.i+a.i*b.r; return o; }

__device__ double su2cg(int j1,int j2,int j3,int m1,int m2,int m3){
  if (m1+m2 != m3) return 0.0;
  int vmin = max(max(-j1+j2+m3, -j1+m1), 0);
  int vmax = min(min(j2+j3+m1, j3-j1+j2), j3+m3);
  if (vmin > vmax) return 0.0;
  double C = sqrt((2.0*j3+1.0)*FACT[j3+j1-j2]*FACT[j3-j1+j2]*FACT[j1+j2-j3]/FACT[j1+j2+j3+1])
           * sqrt(FACT[j3+m3]*FACT[j3-m3]*FACT[j1-m1]*FACT[j1+m1]*FACT[j2-m2]*FACT[j2+m2]);
  double S = 0.0;
  for (int v=vmin; v<=vmax; v++){
    double sgn = ((v+j2+m2)&1) ? -1.0 : 1.0;
    S += sgn * FACT[j2+j3+m1-v]*FACT[j1-m1+v]
         / (FACT[v]*FACT[j3-j1+j2-v]*FACT[j3+m3-v]*FACT[v+j1-j2-m3]);
  }
  return C*S;
}

// real->complex change-of-basis matrix, times (-i)^l (e3nn convention)
__device__ void buildQ(int l, double* qr, double* qi){
  int d = 2*l+1;
  for (int x=0;x<d*d;x++){ qr[x]=0.0; qi[x]=0.0; }
  const double s2 = 0.70710678118654752440;
  for (int m=-l; m<0; m++){
    int r = l+m;
    qr[r*d + (l-m)] = s2;      // q[l+m, l+|m|] = 1/sqrt2
    qi[r*d + (l+m)] = -s2;     // q[l+m, l-|m|] = -i/sqrt2
  }
  qr[l*d+l] = 1.0;
  for (int m=1; m<=l; m++){
    int r=l+m; double sg = (m&1)? -1.0 : 1.0;
    qr[r*d + (l+m)] = sg*s2;   // (-1)^m/sqrt2
    qi[r*d + (l-m)] = sg*s2;   // i*(-1)^m/sqrt2
  }
  int ph = l & 3;              // multiply by (-i)^l
  if (ph){
    for (int x=0;x<d*d;x++){
      double a=qr[x], b=qi[x];
      if (ph==1){ qr[x]=b;  qi[x]=-a; }
      else if (ph==2){ qr[x]=-a; qi[x]=-b; }
      else { qr[x]=-b; qi[x]=a; }
    }
  }
}

// Stage 1: one block per path (19 blocks run concurrently on separate CUs).
extern "C" __global__ void __launch_bounds__(256)
setup_cg(float* wsCg){
  __shared__ double Q1r[25], Q1i[25], Q2r[25], Q2i[25], Q3r[81], Q3i[81];
  __shared__ double su2[225];
  __shared__ double red[4];
  __shared__ double scaleSh;

  int p = blockIdx.x;
  int tid = threadIdx.x;
  int l1=P_L1[p], l2=P_L2[p], l3=P_L3[p];
  int d1=2*l1+1, d2=2*l2+1, d3=2*l3+1;
  int n = d1*d2*d3;

  if (tid==0)        buildQ(l1,Q1r,Q1i);
  else if (tid==64)  buildQ(l2,Q2r,Q2i);
  else if (tid==128) buildQ(l3,Q3r,Q3i);
  if (tid < n){
    int c = tid % d3; int rem = tid / d3; int b = rem % d2; int a = rem / d2;
    su2[tid] = su2cg(l1,l2,l3, a-l1, b-l2, c-l3);
  }
  __syncthreads();

  double myval = 0.0;
  if (tid < n){
    int c = tid % d3; int rem = tid / d3; int b = rem % d2; int a = rem / d2;
    cpx s; s.r=0.0; s.i=0.0;
    int i1=2*l1-a, k1=2*l2-b, n1=2*l3-c;
    for (int ii=0; ii<2; ii++){
      int i = ii ? i1 : a; if (ii && i1==a) break;
      cpx q1; q1.r=Q1r[i*d1+a]; q1.i=Q1i[i*d1+a];
      for (int kk=0; kk<2; kk++){
        int k = kk ? k1 : b; if (kk && k1==b) break;
        cpx q2; q2.r=Q2r[k*d2+b]; q2.i=Q2i[k*d2+b];
        cpx q12 = cmul(q1,q2);
        for (int nn2=0; nn2<2; nn2++){
          int nn = nn2 ? n1 : c; if (nn2 && n1==c) break;
          cpx q3c; q3c.r=Q3r[nn*d3+c]; q3c.i=-Q3i[nn*d3+c];
          cpx t = cmul(q12, q3c);
          double w = su2[(i*d2+k)*d3+nn];
          s.r += t.r*w; s.i += t.i*w;
        }
      }
    }
    myval = s.r;  // imag part is structurally ~0
  }
  double v = myval*myval;
  for (int off=32; off>0; off>>=1) v += __shfl_down(v, off, 64);
  if ((tid&63)==0) red[tid>>6] = v;
  __syncthreads();
  if (tid==0){
    double tot = red[0]+red[1]+red[2]+red[3];
    scaleSh = sqrt((double)d3) / sqrt(tot);   // 'component' norm: cg *= sqrt(d3)
  }
  __syncthreads();
  if (tid < n) wsCg[P_CGOFF[p] + tid] = (float)(myval * scaleSh);
}

// Stage 2: one block builds the sparse term tables + per-column meta from wsCg.
extern "C" __global__ void __launch_bounds__(256)
setup_tables(const float* __restrict__ wsCg, int* wsHdr, int* wsMeta, int2* wsTerms){
  __shared__ float cgAll[1225];
  __shared__ int counts[NCLASS], ptrs[NCLASS+1];

  int tid = threadIdx.x;
  for (int t = tid; t < 1225; t += 256) cgAll[t] = wsCg[t];
  __syncthreads();

  if (tid < NCLASS){
    int p=0; while (p+1<NPATH && tid >= P_CLSBASE[p+1]) p++;
    int k = tid - P_CLSBASE[p];
    int d1=2*P_L1[p]+1, d2=2*P_L2[p]+1, d3=2*P_L3[p]+1;
    int cnt=0;
    for (int a=0;a<d1;a++) for (int b=0;b<d2;b++)
      if (fabsf(cgAll[P_CGOFF[p] + (a*d2+b)*d3 + k]) > 1e-4f) cnt++;
    counts[tid]=cnt;
  }
  __syncthreads();
  if (tid==0){
    int s=0; for (int q=0;q<NCLASS;q++){ ptrs[q]=s; s+=counts[q]; } ptrs[NCLASS]=s; wsHdr[0]=s;
  }
  __syncthreads();
  if (tid < NCLASS){
    int p=0; while (p+1<NPATH && tid >= P_CLSBASE[p+1]) p++;
    int k = tid - P_CLSBASE[p];
    int d1=2*P_L1[p]+1, d2=2*P_L2[p]+1, d3=2*P_L3[p]+1;
    int w = ptrs[tid];
    for (int a=0;a<d1;a++) for (int b=0;b<d2;b++){
      float val = cgAll[P_CGOFF[p] + (a*d2+b)*d3 + k];
      if (fabsf(val) > 1e-4f){
        int idx = (P_OFF2[p]+b)*240 + a;   // index into P[j][i] (i_local part; x1base added at use)
        wsTerms[w] = make_int2(idx, __float_as_int(val));
        w++;
      }
    }
  }
  for (int c = tid; c < NCOL; c += 256){
    int j=0; while (c >= S_OFF[j+1]) j++;
    int p = S_PATH[j];
    int d3 = 2*P_L3[p]+1;
    int rel = c - S_OFF[j];
    int u = rel / d3, k = rel - u*d3;
    int cls = P_CLSBASE[p] + k;
    int start = ptrs[cls];
    int cnt = ptrs[cls+1]-ptrs[cls];
    int xb = P_OFF1[p] + u*P_D1[p];
    wsMeta[c] = start | (cnt<<11) | (xb<<16);
  }
}

// tp_kernel v2: block processes many rows (2 per iteration).
// Terms table LDS-resident (copied once per block); per-thread meta for its
// 9 owned columns (c = tid + 256*i) register-resident. Inner chain is pure
// LDS: ds_read_b64 term -> 2x ds_read_b32 Pp (rows r0,r0+1) -> 2 FMA.
extern "C" __global__ void __launch_bounds__(256)
tp_kernel(const float* __restrict__ x1, const float* __restrict__ x2,
          float* __restrict__ out,
          const int* __restrict__ meta, const int2* __restrict__ terms,
          const int* __restrict__ hdr, int nrows)
{
  __shared__ float Pp[2][NCOL];      // 17.3 KB
  __shared__ int2  termsS[CAP_TERMS]; // 10.8 KB
  int tid = threadIdx.x;

  int nT = hdr[0];
  for (int t = tid; t < nT; t += 256) termsS[t] = terms[t];

  // cache packed meta for my columns (c = tid + 256*i); i=8 only valid for tid<112
  int mreg[9];
  #pragma unroll
  for (int i = 0; i < 9; i++){
    int c = tid + (i<<8);
    mreg[i] = (c < NCOL) ? meta[c] : 0;   // cnt=0 -> no work
  }
  __syncthreads();

  int npairs = (nrows + 1) >> 1;
  for (int pr = blockIdx.x; pr < npairs; pr += gridDim.x){
    int r0 = pr << 1;
    bool has2 = (r0 + 1) < nrows;

    // stage Pp for the two rows: float4 over 540 quads per row.
    // quad e -> j = e/60, i4 = e%60 ; Pp4[e] = x2[j] * x1row4[i4]
    {
      const float4* x14 = (const float4*)(x1 + (size_t)r0*240);
      const float*  x2r = x2 + (size_t)r0*9;
      float4* P4 = (float4*)Pp[0];
      for (int e = tid; e < 540; e += 256){
        int j = e/60, i4 = e - j*60;
        float4 v = x14[i4];
        float s = x2r[j];
        float4 o; o.x=s*v.x; o.y=s*v.y; o.z=s*v.z; o.w=s*v.w;
        P4[e] = o;
      }
      if (has2){
        const float4* x14b = (const float4*)(x1 + (size_t)(r0+1)*240);
        const float*  x2b = x2 + (size_t)(r0+1)*9;
        float4* P4b = (float4*)Pp[1];
        for (int e = tid; e < 540; e += 256){
          int j = e/60, i4 = e - j*60;
          float4 v = x14b[i4];
          float s = x2b[j];
          float4 o; o.x=s*v.x; o.y=s*v.y; o.z=s*v.z; o.w=s*v.w;
          P4b[e] = o;
        }
      }
    }
    __syncthreads();

    float acc0[9], acc1[9];
    #pragma unroll
    for (int i = 0; i < 9; i++){
      int m = mreg[i];
      int start = m & 2047;
      int cnt = (m>>11)&31;
      int xb = (m>>16)&255;
      float a0 = 0.f, a1 = 0.f;
      for (int t = 0; t < cnt; t++){
        int2 tv = termsS[start+t];
        float val = __int_as_float(tv.y);
        int idx = tv.x + xb;
        a0 += val * Pp[0][idx];
        a1 += val * Pp[1][idx];
      }
      acc0[i] = a0; acc1[i] = a1;
    }

    float* o0 = out + (size_t)r0*NCOL;
    #pragma unroll
    for (int i = 0; i < 9; i++){
      int c = tid + (i<<8);
      if (c < NCOL){
        o0[c] = acc0[i];
        if (has2) o0[NCOL + c] = acc1[i];
      }
    }
    __syncthreads();   // protect Pp before next pair's staging
  }
}

extern "C" void kernel_launch(void* const* d_in, const int* in_sizes, int n_in,
                              void* d_out, int out_size, void* d_ws, size_t ws_size,
                              hipStream_t stream) {
  const float* x1 = (const float*)d_in[0];
  const float* x2 = (const float*)d_in[1];
  float* out = (float*)d_out;
  int nrows = in_sizes[0] / 240;

  int* ws = (int*)d_ws;
  int* hdr   = ws;                    // [0]: nTerms
  int* meta  = ws + 64;               // 2160 ints, 16B-aligned
  int2* terms = (int2*)(ws + 4096);   // capacity 1344 terms (dense bound 1225)
  float* cgbuf = (float*)(ws + 7168); // 1225 floats of normalized CG values

  setup_cg<<<dim3(NPATH), dim3(256), 0, stream>>>(cgbuf);
  setup_tables<<<dim3(1), dim3(256), 0, stream>>>(cgbuf, hdr, meta, terms);

  int npairs = (nrows + 1) >> 1;
  int grid = npairs < 2048 ? npairs : 2048;
  tp_kernel<<<dim3(grid), dim3(256), 0, stream>>>(x1, x2, out, meta, terms, hdr, nrows);
}